// Round 3
// baseline (91.099 us; speedup 1.0000x reference)
//
#include <hip/hip_runtime.h>

#define EPS 1e-8f

constexpr int NROWS = 1024;
constexpr int K     = 256;
constexpr int TM    = 128;   // output tile rows per block
constexpr int TN    = 128;   // output tile cols per block
constexpr int KZ    = 8;     // k slices (split-K)
constexpr int KC    = 32;    // k per slice

// d_ws layout: [0,8KB) sums[2048]; [64KB, 64KB+32MB) partials[KZ][1024][1024]
constexpr size_t PART_OFF = 65536;

using v2f = __attribute__((ext_vector_type(2))) float;
using v4f = __attribute__((ext_vector_type(4))) float;

// ---------------- Kernel A: row sums ----------------
__global__ __launch_bounds__(256) void rowsum_kernel(const float* __restrict__ x,
                                                     const float* __restrict__ y,
                                                     float* __restrict__ sums) {
    const int wave = threadIdx.x >> 6;
    const int lane = threadIdx.x & 63;
    const int row  = blockIdx.x * 4 + wave;   // 0..2047
    const float* src = (row < NROWS) ? (x + (size_t)row * K)
                                     : (y + (size_t)(row - NROWS) * K);
    float4 v = ((const float4*)src)[lane];
    float s = (v.x + v.y) + (v.z + v.w);
    #pragma unroll
    for (int off = 32; off > 0; off >>= 1) s += __shfl_down(s, off);
    if (lane == 0) sums[row] = s;
}

// ---------------- Kernel B: split-K partial min-sums ----------------
// Grid (8,8,8): 128x128 tile x KC=32 slice. 8x8 microtile/thread.
// LDS: 256 rows x 8 float4, XOR-swizzled per region:
//   x rows (0..127):  c4 = col4 ^ (row & 3)      -> a-reads 4 distinct bank quads
//   y rows (128..255):c4 = col4 ^ ((j >> 2) & 7) -> b-reads 2-way alias (free)
// Microtile: rows ty+16r (r<8), cols tx*4+c+64*ch (c<4, ch<2) -> float4 stores.
__global__ __launch_bounds__(256, 2) void partial_kernel(const float* __restrict__ x,
                                                         const float* __restrict__ y,
                                                         float* __restrict__ part) {
    __shared__ v4f lds4[256 * 8];   // 32 KB

    const int tid = threadIdx.x;
    const int rowBase = blockIdx.y * TM;
    const int colBase = blockIdx.x * TN;
    const int kbase   = blockIdx.z * KC;

    // ---- stage: 8 float4 per thread ----
    {
        const int col4 = tid & 7;      // float4 col within 32-float slice
        const int r0   = tid >> 3;     // 0..31
        #pragma unroll
        for (int i = 0; i < 8; ++i) {
            const int row_s = r0 + 32 * i;   // 0..255 (uniform x/y split: i<4 -> x)
            if (row_s < 128) {
                const v4f v = *(const v4f*)&x[(size_t)(rowBase + row_s) * K + kbase + col4 * 4];
                lds4[row_s * 8 + (col4 ^ (row_s & 3))] = v;
            } else {
                const int j = row_s - 128;
                const v4f v = *(const v4f*)&y[(size_t)(colBase + j) * K + kbase + col4 * 4];
                lds4[row_s * 8 + (col4 ^ ((j >> 2) & 7))] = v;
            }
        }
    }
    __syncthreads();

    const int ty = tid >> 4;   // 0..15
    const int tx = tid & 15;
    const int aswz = ty & 3;
    const int bswz = tx & 7;

    v2f acc[8][8];
    #pragma unroll
    for (int r = 0; r < 8; ++r)
        #pragma unroll
        for (int c = 0; c < 8; ++c) acc[r][c] = (v2f){0.0f, 0.0f};

    #pragma unroll
    for (int kk4 = 0; kk4 < KC / 4; ++kk4) {
        v4f b[8];
        const int bcol = kk4 ^ bswz;
        #pragma unroll
        for (int ch = 0; ch < 2; ++ch)
            #pragma unroll
            for (int c = 0; c < 4; ++c)
                b[ch * 4 + c] = lds4[(128 + tx * 4 + c + 64 * ch) * 8 + bcol];

        const int acol = kk4 ^ aswz;
        #pragma unroll
        for (int r = 0; r < 8; ++r) {
            const v4f a = lds4[(ty + 16 * r) * 8 + acol];
            #pragma unroll
            for (int cc = 0; cc < 8; ++cc) {
                const v2f mlo = __builtin_elementwise_min(a.lo, b[cc].lo);
                const v2f mhi = __builtin_elementwise_min(a.hi, b[cc].hi);
                acc[r][cc] += mlo;     // v_pk_add_f32
                acc[r][cc] += mhi;
            }
        }
    }

    // ---- store partials: 16 coalesced float4 per thread ----
    float* p = part + (size_t)blockIdx.z * (NROWS * NROWS);
    #pragma unroll
    for (int r = 0; r < 8; ++r) {
        const size_t rowOff = (size_t)(rowBase + ty + 16 * r) * NROWS + colBase;
        #pragma unroll
        for (int ch = 0; ch < 2; ++ch) {
            v4f o;
            o.x = acc[r][ch * 4 + 0].x + acc[r][ch * 4 + 0].y;
            o.y = acc[r][ch * 4 + 1].x + acc[r][ch * 4 + 1].y;
            o.z = acc[r][ch * 4 + 2].x + acc[r][ch * 4 + 2].y;
            o.w = acc[r][ch * 4 + 3].x + acc[r][ch * 4 + 3].y;
            *(v4f*)&p[rowOff + 64 * ch + tx * 4] = o;
        }
    }
}

// ---------------- Kernel C: combine partials + epilogue ----------------
__global__ __launch_bounds__(256) void combine_kernel(const float* __restrict__ part,
                                                      const float* __restrict__ sums,
                                                      float* __restrict__ out) {
    const int idx4 = blockIdx.x * 256 + threadIdx.x;  // 0..262143
    const int row  = idx4 >> 8;
    const int col4 = idx4 & 255;
    constexpr int SL = NROWS * NROWS / 4;

    const v4f* p4 = (const v4f*)part;
    v4f s01 = p4[idx4]           + p4[idx4 + SL];
    v4f s23 = p4[idx4 + 2 * SL]  + p4[idx4 + 3 * SL];
    v4f s45 = p4[idx4 + 4 * SL]  + p4[idx4 + 5 * SL];
    v4f s67 = p4[idx4 + 6 * SL]  + p4[idx4 + 7 * SL];
    v4f n = (s01 + s23) + (s45 + s67);

    const float sx = sums[row];
    const v4f   sy = *(const v4f*)&sums[NROWS + col4 * 4];

    v4f o;
    o.x = n.x / (sx + sy.x - n.x + EPS);
    o.y = n.y / (sx + sy.y - n.y + EPS);
    o.z = n.z / (sx + sy.z - n.z + EPS);
    o.w = n.w / (sx + sy.w - n.w + EPS);
    ((v4f*)out)[idx4] = o;
}

extern "C" void kernel_launch(void* const* d_in, const int* in_sizes, int n_in,
                              void* d_out, int out_size, void* d_ws, size_t ws_size,
                              hipStream_t stream) {
    const float* x = (const float*)d_in[0];
    const float* y = (const float*)d_in[1];
    float* out   = (float*)d_out;
    float* sums  = (float*)d_ws;
    float* parts = (float*)((char*)d_ws + PART_OFF);

    rowsum_kernel<<<dim3(2048 / 4), dim3(256), 0, stream>>>(x, y, sums);
    partial_kernel<<<dim3(NROWS / TN, NROWS / TM, KZ), dim3(256), 0, stream>>>(x, y, parts);
    combine_kernel<<<dim3(NROWS * NROWS / 4 / 256), dim3(256), 0, stream>>>(parts, sums, out);
}

// Round 4
// 85.810 us; speedup vs baseline: 1.0616x; 1.0616x over previous
//
#include <hip/hip_runtime.h>

#define EPS 1e-8f

constexpr int NROWS = 1024;
constexpr int K     = 256;
constexpr int TILE  = 64;   // 64x64 output tile per block
constexpr int KC    = 64;   // k chunk (double-buffered)
constexpr int NCH   = K / KC;

// ---------------- Kernel A: row sums ----------------
__global__ __launch_bounds__(256) void rowsum_kernel(const float* __restrict__ x,
                                                     const float* __restrict__ y,
                                                     float* __restrict__ sums) {
    const int wave = threadIdx.x >> 6;
    const int lane = threadIdx.x & 63;
    const int row  = blockIdx.x * 4 + wave;   // 0..2047
    const float* src = (row < NROWS) ? (x + (size_t)row * K)
                                     : (y + (size_t)(row - NROWS) * K);
    float4 v = ((const float4*)src)[lane];
    float s = (v.x + v.y) + (v.z + v.w);
    #pragma unroll
    for (int off = 32; off > 0; off >>= 1) s += __shfl_down(s, off);
    if (lane == 0) sums[row] = s;
}

// ---------------- Kernel B: fused Ruzicka ----------------
// Grid (16,16), 256 threads. LDS: 2 x (128 rows x 64 floats), rows 0..63 = x-tile,
// 64..127 = y-tile. Swizzle: float4 col c stored at c ^ ((row>>2)&7).
//  a-reads (row=ty*4+r): swz=ty&7 -> 4 distinct bank-quads, broadcast x16. free.
//  b-reads (row=64+tx*4+c): swz=tx&7 -> 8 quads, 2 addrs each. free.
//  staging writes: per 16-lane phase one full row -> all 32 banks. free.
__global__ __launch_bounds__(256) void ruzicka_kernel(const float* __restrict__ x,
                                                      const float* __restrict__ y,
                                                      const float* __restrict__ sums,
                                                      float* __restrict__ out) {
    __shared__ float buf[2][128][KC];   // 64 KB

    const int tid = threadIdx.x;
    const int rowBase = blockIdx.y * TILE;
    const int colBase = blockIdx.x * TILE;

    // loader mapping: 16 float4-cols x 16 rows, 8 row-passes
    const int l_c4 = tid & 15;
    const int l_r0 = tid >> 4;

    float4 pf[8];

    auto gload = [&](int ch) {
        #pragma unroll
        for (int i = 0; i < 8; ++i) {
            const int rs = l_r0 + 16 * i;            // 0..127
            const int gr = (rs < TILE) ? (rowBase + rs) : (colBase + rs - TILE);
            const float* src = (rs < TILE) ? x : y;
            pf[i] = *(const float4*)&src[(size_t)gr * K + ch * KC + l_c4 * 4];
        }
    };
    auto swrite = [&](int b) {
        #pragma unroll
        for (int i = 0; i < 8; ++i) {
            const int rs = l_r0 + 16 * i;
            const int c4 = l_c4 ^ ((rs >> 2) & 7);
            *(float4*)&buf[b][rs][c4 * 4] = pf[i];
        }
    };

    const int ty = tid >> 4;     // 0..15 -> rows ty*4+r
    const int tx = tid & 15;     // 0..15 -> cols tx*4+c
    const int aswz = ty & 7;
    const int bswz = tx & 7;

    float acc[4][4];
    #pragma unroll
    for (int r = 0; r < 4; ++r)
        #pragma unroll
        for (int c = 0; c < 4; ++c) acc[r][c] = 0.0f;

    gload(0);
    swrite(0);
    __syncthreads();

    for (int ch = 0; ch < NCH; ++ch) {
        if (ch + 1 < NCH) gload(ch + 1);   // prefetch next chunk into regs

        const float (*B)[KC] = buf[ch & 1];
        #pragma unroll 4
        for (int k4 = 0; k4 < KC / 4; ++k4) {
            float4 a[4], b[4];
            const int ak = (k4 ^ aswz) * 4;
            const int bk = (k4 ^ bswz) * 4;
            #pragma unroll
            for (int r = 0; r < 4; ++r) a[r] = *(const float4*)&B[ty * 4 + r][ak];
            #pragma unroll
            for (int c = 0; c < 4; ++c) b[c] = *(const float4*)&B[TILE + tx * 4 + c][bk];
            #pragma unroll
            for (int r = 0; r < 4; ++r)
                #pragma unroll
                for (int c = 0; c < 4; ++c) {
                    const float m0 = fminf(a[r].x, b[c].x);
                    const float m1 = fminf(a[r].y, b[c].y);
                    const float m2 = fminf(a[r].z, b[c].z);
                    const float m3 = fminf(a[r].w, b[c].w);
                    acc[r][c] += (m0 + m1) + (m2 + m3);
                }
        }

        if (ch + 1 < NCH) {
            swrite((ch + 1) & 1);   // other buffer: safe while others still compute
            __syncthreads();
        }
    }

    // epilogue: den = Sx + Sy - num
    float sx[4];
    #pragma unroll
    for (int r = 0; r < 4; ++r) sx[r] = sums[rowBase + ty * 4 + r];
    const float4 sy = *(const float4*)&sums[NROWS + colBase + tx * 4];

    #pragma unroll
    for (int r = 0; r < 4; ++r) {
        float4 o;
        o.x = acc[r][0] / (sx[r] + sy.x - acc[r][0] + EPS);
        o.y = acc[r][1] / (sx[r] + sy.y - acc[r][1] + EPS);
        o.z = acc[r][2] / (sx[r] + sy.z - acc[r][2] + EPS);
        o.w = acc[r][3] / (sx[r] + sy.w - acc[r][3] + EPS);
        *(float4*)&out[(size_t)(rowBase + ty * 4 + r) * NROWS + colBase + tx * 4] = o;
    }
}

extern "C" void kernel_launch(void* const* d_in, const int* in_sizes, int n_in,
                              void* d_out, int out_size, void* d_ws, size_t ws_size,
                              hipStream_t stream) {
    const float* x = (const float*)d_in[0];
    const float* y = (const float*)d_in[1];
    float* out  = (float*)d_out;
    float* sums = (float*)d_ws;   // 2048 floats

    rowsum_kernel<<<dim3(2048 / 4), dim3(256), 0, stream>>>(x, y, sums);
    ruzicka_kernel<<<dim3(NROWS / TILE, NROWS / TILE), dim3(256), 0, stream>>>(x, y, sums, out);
}